// Round 1
// baseline (279.795 us; speedup 1.0000x reference)
//
#include <hip/hip_runtime.h>

#define TPB 256

// Kernel 1: per-block expert histogram. blockHist[b*E + e] = count of expert e in block b's chunk.
__global__ void k_hist(const int* __restrict__ eidx, int* __restrict__ blockHist,
                       int NK, int E) {
    __shared__ int hist[256];
    int tid = threadIdx.x;
    for (int e = tid; e < E; e += TPB) hist[e] = 0;
    __syncthreads();
    int j = blockIdx.x * TPB + tid;
    if (j < NK) atomicAdd(&hist[eidx[j]], 1);
    __syncthreads();
    for (int e = tid; e < E; e += TPB)
        blockHist[(size_t)blockIdx.x * E + e] = hist[e];
}

// Kernel 2 (single block): per-expert scan over blocks (blockHist -> exclusive block prefix),
// cross-expert exclusive scan (offsets), and the inclusive cumsum output (as float).
__global__ void k_scan(int* __restrict__ blockHist, int* __restrict__ offsets,
                       float* __restrict__ cumsum_out, int numBlocks, int E) {
    __shared__ int counts[256];
    int tid = threadIdx.x;
    for (int e = tid; e < E; e += TPB) {
        int total = 0;
        for (int b = 0; b < numBlocks; ++b) {
            size_t idx = (size_t)b * E + e;
            int v = blockHist[idx];
            blockHist[idx] = total;
            total += v;
        }
        counts[e] = total;
    }
    __syncthreads();
    if (tid == 0) {
        int run = 0;
        for (int e = 0; e < E; ++e) {
            offsets[e] = run;
            run += counts[e];
            cumsum_out[e] = (float)run;
        }
    }
}

// Kernel 3: stable position per flat slot. pos = offsets[e] + blockPrefix[b][e] + localRank.
// Writes expanded_row_idx (by j, coalesced), expanded_scale (scattered by pos),
// and srcRow[pos] = token row for the gather kernel.
__global__ void k_pos(const int* __restrict__ eidx, const float* __restrict__ scale,
                      const int* __restrict__ blockHist, const int* __restrict__ offsets,
                      float* __restrict__ row_idx_out, float* __restrict__ scale_out,
                      int* __restrict__ srcRow, int NK, int E, int K) {
    __shared__ unsigned short se[TPB];
    int tid = threadIdx.x;
    int j = blockIdx.x * TPB + tid;
    int e = 0xFFFF;
    if (j < NK) e = eidx[j];
    se[tid] = (unsigned short)e;
    __syncthreads();
    if (j < NK) {
        unsigned short me = (unsigned short)e;
        int rank = 0;
        for (int t = 0; t < tid; ++t)
            rank += (se[t] == me) ? 1 : 0;
        int pos = offsets[e] + blockHist[(size_t)blockIdx.x * E + e] + rank;
        row_idx_out[j] = (float)pos;
        int tok = j / K;
        srcRow[pos] = tok;
        scale_out[pos] = scale[tok];
    }
}

// Kernel 4: row gather. One block per output row; 256 threads x float4 = 4KB row.
__global__ void k_gather(const float* __restrict__ x, const int* __restrict__ srcRow,
                         float* __restrict__ out, int H) {
    int row = blockIdx.x;
    int src = srcRow[row];
    const float4* xs = (const float4*)(x + (size_t)src * H);
    float4* od = (float4*)(out + (size_t)row * H);
    int n4 = H >> 2;
    for (int t = threadIdx.x; t < n4; t += blockDim.x)
        od[t] = xs[t];
}

extern "C" void kernel_launch(void* const* d_in, const int* in_sizes, int n_in,
                              void* d_out, int out_size, void* d_ws, size_t ws_size,
                              hipStream_t stream) {
    const float* x     = (const float*)d_in[0];
    const int*   eidx  = (const int*)d_in[1];
    const float* scale = (const float*)d_in[2];

    const int N  = in_sizes[2];            // scale has N elements
    const int H  = in_sizes[0] / N;        // 1024
    const int K  = in_sizes[1] / N;        // 8
    const int NK = N * K;                  // 131072
    // out_size = NK*H + NK + E + NK  =>  E recovered on host (no device read needed)
    const int E  = out_size - (int)((long long)NK * H) - 2 * NK;   // 64

    const int numBlocks = (NK + TPB - 1) / TPB;  // 512

    // d_out layout (all float)
    float* out_x     = (float*)d_out;
    float* out_rowix = out_x + (size_t)NK * H;
    float* out_cum   = out_rowix + NK;
    float* out_scale = out_cum + E;

    // d_ws layout (ints)
    int* blockHist = (int*)d_ws;                       // numBlocks * E
    int* offsets   = blockHist + (size_t)numBlocks * E; // E
    int* srcRow    = offsets + E;                       // NK

    k_hist<<<numBlocks, TPB, 0, stream>>>(eidx, blockHist, NK, E);
    k_scan<<<1, TPB, 0, stream>>>(blockHist, offsets, out_cum, numBlocks, E);
    k_pos<<<numBlocks, TPB, 0, stream>>>(eidx, scale, blockHist, offsets,
                                         out_rowix, out_scale, srcRow, NK, E, K);
    k_gather<<<NK, TPB, 0, stream>>>(x, srcRow, out_x, H);
}

// Round 5
// 178.407 us; speedup vs baseline: 1.5683x; 1.5683x over previous
//
#include <hip/hip_runtime.h>

#define TPB 256

typedef float f32x4 __attribute__((ext_vector_type(4)));

// Kernel 1: per-block expert histogram. blockHist[b*E + e] = count of expert e in block b's chunk.
__global__ void k_hist(const int* __restrict__ eidx, int* __restrict__ blockHist,
                       int NK, int E) {
    __shared__ int hist[256];
    int tid = threadIdx.x;
    for (int e = tid; e < E; e += TPB) hist[e] = 0;
    __syncthreads();
    int j = blockIdx.x * TPB + tid;
    if (j < NK) atomicAdd(&hist[eidx[j]], 1);
    __syncthreads();
    for (int e = tid; e < E; e += TPB)
        blockHist[(size_t)blockIdx.x * E + e] = hist[e];
}

// Kernel 2a: one block per expert — parallel exclusive scan of that expert's
// per-block counts (numBlocks values), written back in place; total -> counts[e].
__global__ void k_scan_blocks(int* __restrict__ blockHist, int* __restrict__ counts,
                              int numBlocks, int E) {
    __shared__ int s[TPB];
    int e = blockIdx.x;
    int tid = threadIdx.x;
    int per = (numBlocks + TPB - 1) / TPB;
    int start = tid * per;
    int end = start + per; if (end > numBlocks) end = numBlocks;
    int sum = 0;
    for (int b = start; b < end; ++b) sum += blockHist[(size_t)b * E + e];
    s[tid] = sum;
    __syncthreads();
    // Hillis-Steele inclusive scan over 256 thread-sums
    for (int off = 1; off < TPB; off <<= 1) {
        int t = (tid >= off) ? s[tid - off] : 0;
        __syncthreads();
        s[tid] += t;
        __syncthreads();
    }
    int run = (tid == 0) ? 0 : s[tid - 1];   // exclusive prefix of this thread's chunk
    if (tid == TPB - 1) counts[e] = s[tid];
    for (int b = start; b < end; ++b) {
        size_t idx = (size_t)b * E + e;
        int v = blockHist[idx];
        blockHist[idx] = run;
        run += v;
    }
}

// Kernel 2b (1 wave): cross-expert exclusive scan -> offsets; inclusive cumsum -> out (float).
__global__ void k_scan_experts(const int* __restrict__ counts, int* __restrict__ offsets,
                               float* __restrict__ cumsum_out, int E) {
    if (threadIdx.x == 0) {
        int run = 0;
        for (int e = 0; e < E; ++e) {
            offsets[e] = run;
            run += counts[e];
            cumsum_out[e] = (float)run;
        }
    }
}

// Kernel 3: stable position per flat slot. pos = offsets[e] + blockPrefix[b][e] + localRank.
__global__ void k_pos(const int* __restrict__ eidx, const float* __restrict__ scale,
                      const int* __restrict__ blockHist, const int* __restrict__ offsets,
                      float* __restrict__ row_idx_out, float* __restrict__ scale_out,
                      int* __restrict__ srcRow, int NK, int E, int K) {
    __shared__ unsigned short se[TPB];
    int tid = threadIdx.x;
    int j = blockIdx.x * TPB + tid;
    int e = 0xFFFF;
    if (j < NK) e = eidx[j];
    se[tid] = (unsigned short)e;
    __syncthreads();
    if (j < NK) {
        unsigned short me = (unsigned short)e;
        int rank = 0;
        for (int t = 0; t < tid; ++t)
            rank += (se[t] == me) ? 1 : 0;
        int pos = offsets[e] + blockHist[(size_t)blockIdx.x * E + e] + rank;
        row_idx_out[j] = (float)pos;
        int tok = j / K;
        srcRow[pos] = tok;
        scale_out[pos] = scale[tok];
    }
}

// Kernel 4: row gather, grid-stride over rows. 256 threads x float4 = 4KB per row pass.
// Nontemporal stores keep the 537MB output stream from evicting x out of L2.
__global__ void k_gather(const float* __restrict__ x, const int* __restrict__ srcRow,
                         float* __restrict__ out, int H, int NK) {
    int n4 = H >> 2;
    for (int row = blockIdx.x; row < NK; row += gridDim.x) {
        int src = srcRow[row];
        const f32x4* xs = (const f32x4*)(x + (size_t)src * H);
        f32x4* od = (f32x4*)(out + (size_t)row * H);
        for (int t = threadIdx.x; t < n4; t += blockDim.x) {
            f32x4 v = xs[t];
            __builtin_nontemporal_store(v, od + t);
        }
    }
}

extern "C" void kernel_launch(void* const* d_in, const int* in_sizes, int n_in,
                              void* d_out, int out_size, void* d_ws, size_t ws_size,
                              hipStream_t stream) {
    const float* x     = (const float*)d_in[0];
    const int*   eidx  = (const int*)d_in[1];
    const float* scale = (const float*)d_in[2];

    const int N  = in_sizes[2];            // scale has N elements
    const int H  = in_sizes[0] / N;        // 1024
    const int K  = in_sizes[1] / N;        // 8
    const int NK = N * K;                  // 131072
    const int E  = out_size - (int)((long long)NK * H) - 2 * NK;   // 64

    const int numBlocks = (NK + TPB - 1) / TPB;  // 512

    // d_out layout (all float)
    float* out_x     = (float*)d_out;
    float* out_rowix = out_x + (size_t)NK * H;
    float* out_cum   = out_rowix + NK;
    float* out_scale = out_cum + E;

    // d_ws layout (ints)
    int* blockHist = (int*)d_ws;                        // numBlocks * E
    int* counts    = blockHist + (size_t)numBlocks * E; // E
    int* offsets   = counts + E;                        // E
    int* srcRow    = offsets + E;                       // NK

    k_hist<<<numBlocks, TPB, 0, stream>>>(eidx, blockHist, NK, E);
    k_scan_blocks<<<E, TPB, 0, stream>>>(blockHist, counts, numBlocks, E);
    k_scan_experts<<<1, 64, 0, stream>>>(counts, offsets, out_cum, E);
    k_pos<<<numBlocks, TPB, 0, stream>>>(eidx, scale, blockHist, offsets,
                                         out_rowix, out_scale, srcRow, NK, E, K);

    int gblocks = NK < 4096 ? NK : 4096;
    k_gather<<<gblocks, TPB, 0, stream>>>(x, srcRow, out_x, H, NK);
}

// Round 6
// 127.368 us; speedup vs baseline: 2.1967x; 1.4007x over previous
//
#include <hip/hip_runtime.h>

#define TPB 256

typedef float f32x4 __attribute__((ext_vector_type(4)));

// Kernel 1: per-block expert histogram. blockHist[b*E + e] = count of expert e in block b's chunk.
__global__ void k_hist(const int* __restrict__ eidx, int* __restrict__ blockHist,
                       int NK, int E) {
    __shared__ int hist[256];
    int tid = threadIdx.x;
    for (int e = tid; e < E; e += TPB) hist[e] = 0;
    __syncthreads();
    int j = blockIdx.x * TPB + tid;
    if (j < NK) atomicAdd(&hist[eidx[j]], 1);
    __syncthreads();
    for (int e = tid; e < E; e += TPB)
        blockHist[(size_t)blockIdx.x * E + e] = hist[e];
}

// Kernel 2a: one block per expert — parallel exclusive scan of that expert's
// per-block counts (numBlocks values), written back in place; total -> counts[e].
__global__ void k_scan_blocks(int* __restrict__ blockHist, int* __restrict__ counts,
                              int numBlocks, int E) {
    __shared__ int s[TPB];
    int e = blockIdx.x;
    int tid = threadIdx.x;
    int per = (numBlocks + TPB - 1) / TPB;
    int start = tid * per;
    int end = start + per; if (end > numBlocks) end = numBlocks;
    int sum = 0;
    for (int b = start; b < end; ++b) sum += blockHist[(size_t)b * E + e];
    s[tid] = sum;
    __syncthreads();
    // Hillis-Steele inclusive scan over 256 thread-sums
    for (int off = 1; off < TPB; off <<= 1) {
        int t = (tid >= off) ? s[tid - off] : 0;
        __syncthreads();
        s[tid] += t;
        __syncthreads();
    }
    int run = (tid == 0) ? 0 : s[tid - 1];   // exclusive prefix of this thread's chunk
    if (tid == TPB - 1) counts[e] = s[tid];
    for (int b = start; b < end; ++b) {
        size_t idx = (size_t)b * E + e;
        int v = blockHist[idx];
        blockHist[idx] = run;
        run += v;
    }
}

// Kernel 2b (1 wave): cross-expert exclusive scan -> offsets; inclusive cumsum -> out (float).
__global__ void k_scan_experts(const int* __restrict__ counts, int* __restrict__ offsets,
                               float* __restrict__ cumsum_out, int E) {
    if (threadIdx.x == 0) {
        int run = 0;
        for (int e = 0; e < E; ++e) {
            offsets[e] = run;
            run += counts[e];
            cumsum_out[e] = (float)run;
        }
    }
}

// Kernel 3: stable position per flat slot. pos = offsets[e] + blockPrefix[b][e] + localRank.
// Writes expanded_row_idx (coalesced by j), expanded_scale (scattered by pos),
// and dstPos[j] = pos for the scatter kernel.
__global__ void k_pos(const int* __restrict__ eidx, const float* __restrict__ scale,
                      const int* __restrict__ blockHist, const int* __restrict__ offsets,
                      float* __restrict__ row_idx_out, float* __restrict__ scale_out,
                      int* __restrict__ dstPos, int NK, int E, int K) {
    __shared__ unsigned short se[TPB];
    int tid = threadIdx.x;
    int j = blockIdx.x * TPB + tid;
    int e = 0xFFFF;
    if (j < NK) e = eidx[j];
    se[tid] = (unsigned short)e;
    __syncthreads();
    if (j < NK) {
        unsigned short me = (unsigned short)e;
        int rank = 0;
        for (int t = 0; t < tid; ++t)
            rank += (se[t] == me) ? 1 : 0;
        int pos = offsets[e] + blockHist[(size_t)blockIdx.x * E + e] + rank;
        row_idx_out[j] = (float)pos;
        dstPos[j] = pos;
        scale_out[pos] = scale[j / K];
    }
}

// Kernel 4: row SCATTER. One block per token: read x row ONCE (sequential HBM read,
// 64MB total regardless of cache behavior), write K destination rows with NT stores.
// This removes the gather's L3-thrash where the 537MB write stream evicted x and
// forced ~537MB of HBM re-reads.
__global__ void k_scatter(const float* __restrict__ x, const int* __restrict__ dstPos,
                          float* __restrict__ out, int H, int K, int N) {
    __shared__ int pos_s[32];   // K <= 32
    int n4 = H >> 2;
    int tok = blockIdx.x;
    if (tok >= N) return;
    if (threadIdx.x < K) pos_s[threadIdx.x] = dstPos[tok * K + threadIdx.x];
    __syncthreads();
    const f32x4* xs = (const f32x4*)(x + (size_t)tok * H);
    for (int t = threadIdx.x; t < n4; t += blockDim.x) {
        f32x4 v = xs[t];
        #pragma unroll
        for (int k = 0; k < 8; ++k) {   // K == 8 for this problem; guard anyway
            if (k < K) {
                f32x4* od = (f32x4*)(out + (size_t)pos_s[k] * H);
                __builtin_nontemporal_store(v, od + t);
            }
        }
    }
}

extern "C" void kernel_launch(void* const* d_in, const int* in_sizes, int n_in,
                              void* d_out, int out_size, void* d_ws, size_t ws_size,
                              hipStream_t stream) {
    const float* x     = (const float*)d_in[0];
    const int*   eidx  = (const int*)d_in[1];
    const float* scale = (const float*)d_in[2];

    const int N  = in_sizes[2];            // scale has N elements
    const int H  = in_sizes[0] / N;        // 1024
    const int K  = in_sizes[1] / N;        // 8
    const int NK = N * K;                  // 131072
    const int E  = out_size - (int)((long long)NK * H) - 2 * NK;   // 64

    const int numBlocks = (NK + TPB - 1) / TPB;  // 512

    // d_out layout (all float)
    float* out_x     = (float*)d_out;
    float* out_rowix = out_x + (size_t)NK * H;
    float* out_cum   = out_rowix + NK;
    float* out_scale = out_cum + E;

    // d_ws layout (ints)
    int* blockHist = (int*)d_ws;                        // numBlocks * E
    int* counts    = blockHist + (size_t)numBlocks * E; // E
    int* offsets   = counts + E;                        // E
    int* dstPos    = offsets + E;                       // NK

    k_hist<<<numBlocks, TPB, 0, stream>>>(eidx, blockHist, NK, E);
    k_scan_blocks<<<E, TPB, 0, stream>>>(blockHist, counts, numBlocks, E);
    k_scan_experts<<<1, 64, 0, stream>>>(counts, offsets, out_cum, E);
    k_pos<<<numBlocks, TPB, 0, stream>>>(eidx, scale, blockHist, offsets,
                                         out_rowix, out_scale, dstPos, NK, E, K);
    k_scatter<<<N, TPB, 0, stream>>>(x, dstPos, out_x, H, K, N);
}